// Round 1
// 3042.892 us; speedup vs baseline: 1.8068x; 1.8068x over previous
//
#include <hip/hip_runtime.h>
#include <stdint.h>

// Problem constants
#define B_   128
#define C_   512
#define P_   196
#define T_   32
#define V_   10403
#define E_   128
#define U_   256
#define KX_  896     // C+E+U : X row width in PAIRED u32 units (attn|emb|h)
#define K2_  1792    // doubled K for hi/lo split GEMM
#define NPAD_ 10496  // 82 * 128, padded N for the logits GEMM

typedef unsigned short u16;
typedef __attribute__((ext_vector_type(8))) short bf16x8;
typedef __attribute__((ext_vector_type(4))) float f32x4;

__device__ __forceinline__ float b2f(u16 u){
  union { unsigned int i; float f; } v; v.i = ((unsigned int)u) << 16; return v.f;
}
__device__ __forceinline__ u16 f2b(float f){
  union { float f; unsigned int i; } v; v.f = f;
  unsigned int r = (v.i + 0x7FFFu + ((v.i >> 16) & 1u)) >> 16;
  return (u16)r;
}
__device__ __forceinline__ unsigned int pk2(float a, float b){
  return (unsigned int)f2b(a) | ((unsigned int)f2b(b) << 16);
}
// duplicate one bf16 value into both halves of a u32 (X element for K-doubled GEMM)
__device__ __forceinline__ unsigned int dup(float a){
  return (unsigned int)f2b(a) * 0x00010001u;
}
// hi/lo split of fp32 weight into two bf16 halves packed in one u32
__device__ __forceinline__ unsigned int hl(float w){
  u16 h = f2b(w);
  float lo = w - b2f(h);
  return (unsigned int)h | ((unsigned int)f2b(lo) << 16);
}

// ---------------- mean over P (image_features [B,C,P] fp32) ------------
__global__ void k_mean(const float* __restrict__ imf, float* __restrict__ mean){
  int idx = blockIdx.x * 256 + threadIdx.x;          // b*C + c, 65536 total
  const float4* p4 = (const float4*)(imf + (size_t)idx * P_);
  float s = 0.f;
  for (int i = 0; i < 49; ++i){
    float4 q = p4[i];
    s += q.x + q.y + q.z + q.w;
  }
  mean[idx] = s * (1.f / 196.f);
}

// ---------------- h0 = mean@W_h0^T + b_h0 ; c0 = mean@W_c0^T + b_c0 ----
__global__ void k_h0c0(const float* __restrict__ mean,
                       const float* __restrict__ Wh, const float* __restrict__ bh,
                       const float* __restrict__ Wc, const float* __restrict__ bc,
                       float* __restrict__ h0, float* __restrict__ c0){
  int idx = blockIdx.x * 256 + threadIdx.x;          // b*512 + j
  int b = idx >> 9, j = idx & 511;
  int u = j & 255, isc = j >> 8;
  const float* wr = (isc ? Wc : Wh) + (size_t)u * C_;
  const float* m = mean + b * C_;
  float s = 0.f;
  for (int c = 0; c < C_; ++c) s += m[c] * wr[c];
  s += (isc ? bc : bh)[u];
  (isc ? c0 : h0)[b * U_ + u] = s;
}

// ---------------- qk[b,c] = sum_u q[b,u]*W_key[u,c] --------------------
__global__ void k_qk(const float* __restrict__ q, const float* __restrict__ Wk,
                     float* __restrict__ qk){
  int idx = blockIdx.x * 256 + threadIdx.x;          // b*512 + c
  int b = idx >> 9;
  int c = idx & 511;
  const float* qb = q + b * U_;
  float s = 0.f;
  for (int u = 0; u < U_; ++u) s += qb[u] * Wk[u * C_ + c];
  qk[idx] = s;
}

// ---------------- attention: scores -> softmax -> attn; fill X ---------
__global__ void __launch_bounds__(256) k_attn(
    const float* __restrict__ imf, const float* __restrict__ qk_g,
    const int* __restrict__ cap, const float* __restrict__ emb,
    float* __restrict__ attn_ws, unsigned int* __restrict__ X,
    float* __restrict__ maps, int t)
{
  __shared__ __align__(16) float qk[C_];
  __shared__ __align__(16) float red[256];
  __shared__ __align__(16) float wl[P_];
  int b = blockIdx.x, tid = threadIdx.x;
  qk[tid]       = qk_g[b * C_ + tid];
  qk[tid + 256] = qk_g[b * C_ + 256 + tid];
  __syncthreads();
  float s = -1e30f;
  if (tid < P_){
    float acc = 0.f;
    const float* base = imf + (size_t)b * C_ * P_ + tid;
    for (int c = 0; c < C_; ++c) acc += qk[c] * base[c * P_];
    s = acc * 0.0625f;   // 1/sqrt(256)
  }
  red[tid] = s; __syncthreads();
  for (int off = 128; off > 0; off >>= 1){
    if (tid < off) red[tid] = fmaxf(red[tid], red[tid + off]);
    __syncthreads();
  }
  float mx = red[0]; __syncthreads();
  float e = (tid < P_) ? __expf(s - mx) : 0.f;
  red[tid] = e; __syncthreads();
  for (int off = 128; off > 0; off >>= 1){
    if (tid < off) red[tid] += red[tid + off];
    __syncthreads();
  }
  float inv = 1.f / red[0];
  if (tid < P_){
    float w = e * inv;
    wl[tid] = w;
    maps[(size_t)(b * T_ + t) * P_ + tid] = w;
  }
  __syncthreads();
  size_t xrow = (size_t)(b * T_ + t) * KX_;
  for (int c = tid; c < C_; c += 256){
    const float4* p4 = (const float4*)(imf + ((size_t)b * C_ + c) * P_);
    float a = 0.f;
    for (int i = 0; i < 49; ++i){
      float4 q4 = p4[i];
      a += wl[4*i]   * q4.x + wl[4*i+1] * q4.y
         + wl[4*i+2] * q4.z + wl[4*i+3] * q4.w;
    }
    attn_ws[b * C_ + c] = a;
    X[xrow + c] = dup(a);
  }
  if (tid < E_){
    int ix = cap[b * T_ + t];
    X[xrow + C_ + tid] = dup(emb[(size_t)ix * E_ + tid]);
  }
}

// ---------------- gates GEMM (MFMA) + LSTM pointwise -------------------
// grid 128 = 8 b-tiles(16) x 16 u-tiles(16); 4 waves, wave = gate index.
__global__ void __launch_bounds__(256) k_gates(
    const float* __restrict__ Wih, const float* __restrict__ bih,
    const float* __restrict__ Whh, const float* __restrict__ bhh,
    const int* __restrict__ cap, const float* __restrict__ emb,
    const float* __restrict__ attn_ws, const float* __restrict__ hprev,
    float* __restrict__ c_st, float* __restrict__ hnew,
    unsigned int* __restrict__ X, int t)
{
  __shared__ __align__(16) u16 xg[16 * 32];
  __shared__ __align__(16) u16 wt[64 * 32];
  __shared__ __align__(16) float gl[4 * 16 * 16];
  __shared__ int ixl[16];
  int tid = threadIdx.x;
  int b0 = (blockIdx.x >> 4) * 16;
  int u0 = (blockIdx.x & 15) * 16;
  if (tid < 16) ixl[tid] = cap[(b0 + tid) * T_ + t];
  __syncthreads();
  int lane = tid & 63, wv = tid >> 6;
  int quad = lane >> 4, l15 = lane & 15;
  f32x4 acc = {0.f, 0.f, 0.f, 0.f};
  for (int kc = 0; kc < 28; ++kc){
    int k0 = kc * 32;
    // stage xg[16][32]: k<128 emb, 128..639 attn, 640..895 h  (f32 -> bf16)
    for (int e2 = tid; e2 < 512; e2 += 256){
      int r = e2 >> 5, kk = e2 & 31, k = k0 + kk;
      float v;
      if (k < 128)      v = emb[(size_t)ixl[r] * E_ + k];
      else if (k < 640) v = attn_ws[(b0 + r) * C_ + (k - 128)];
      else              v = hprev[(b0 + r) * U_ + (k - 640)];
      xg[e2] = f2b(v);
    }
    // stage wt[64][32]: rows j = g*256 + u0 + r (g=jl>>4, r=jl&15), f32->bf16
    {
      int jl = tid >> 2, seg = tid & 3;
      int g = jl >> 4, r = jl & 15;
      int j = g * 256 + u0 + r;
      const float* src = (kc < 20)
          ? (Wih + (size_t)j * 640 + k0 + seg * 8)
          : (Whh + (size_t)j * 256 + (k0 - 640) + seg * 8);
      float4 lo = ((const float4*)src)[0];
      float4 hi = ((const float4*)src)[1];
      uint4 o;
      o.x = pk2(lo.x, lo.y); o.y = pk2(lo.z, lo.w);
      o.z = pk2(hi.x, hi.y); o.w = pk2(hi.z, hi.w);
      *((uint4*)(wt + jl * 32 + seg * 8)) = o;
    }
    __syncthreads();
    bf16x8 af  = *((const bf16x8*)(xg + l15 * 32 + quad * 8));
    bf16x8 bfv = *((const bf16x8*)(wt + (wv * 16 + l15) * 32 + quad * 8));
    acc = __builtin_amdgcn_mfma_f32_16x16x32_bf16(af, bfv, acc, 0, 0, 0);
    __syncthreads();
  }
  // D: row m = quad*4+reg (b), col n = l15 (u); wave wv = gate
  #pragma unroll
  for (int r = 0; r < 4; ++r)
    gl[(wv << 8) + ((quad * 4 + r) << 4) + l15] = acc[r];
  __syncthreads();
  {
    int br = tid >> 4, ur = tid & 15;
    int b = b0 + br, u = u0 + ur;
    float i_g = gl[(0 << 8) + (br << 4) + ur] + bih[u]       + bhh[u];
    float f_g = gl[(1 << 8) + (br << 4) + ur] + bih[256 + u] + bhh[256 + u];
    float g_g = gl[(2 << 8) + (br << 4) + ur] + bih[512 + u] + bhh[512 + u];
    float o_g = gl[(3 << 8) + (br << 4) + ur] + bih[768 + u] + bhh[768 + u];
    float cold = c_st[b * U_ + u];
    float si = 1.f / (1.f + __expf(-i_g));
    float sf = 1.f / (1.f + __expf(-f_g));
    float so = 1.f / (1.f + __expf(-o_g));
    float cn = sf * cold + si * tanhf(g_g);
    float hn = so * tanhf(cn);
    c_st[b * U_ + u] = cn;
    hnew[b * U_ + u] = hn;
    X[(size_t)(b * T_ + t) * KX_ + 640 + u] = dup(hn);
  }
}

// ---------------- W_out -> hi/lo bf16 pairs, zero-padded to NPAD_ ------
// one float4 per thread; W2 is u32[v][896], u32 = (hi | lo<<16) per k.
__global__ void k_wsplit(const float* __restrict__ Wout,
                         unsigned int* __restrict__ W2){
  int idx = blockIdx.x * 256 + threadIdx.x;        // NPAD_*224 = 2,351,104
  int v = idx / 224, kq = idx - v * 224;
  uint4 o;
  if (v < V_){
    float4 w = ((const float4*)(Wout + (size_t)v * KX_))[kq];
    o.x = hl(w.x); o.y = hl(w.y); o.z = hl(w.z); o.w = hl(w.w);
  } else {
    o.x = o.y = o.z = o.w = 0u;
  }
  ((uint4*)(W2 + (size_t)v * KX_))[kq] = o;
}

// ---------------- logits GEMM: MFMA, m97 structure ---------------------
// C[4096, NPAD_] = A2[4096, K2_] * W2[NPAD_, K2_]^T  (bf16, K doubled hi/lo)
// 128x128 tile, BK=32, 4 waves (2x2), 4x4 frags of 16x16x32 per wave.
__global__ void __launch_bounds__(256) k_logits(
    const u16* __restrict__ A2, const u16* __restrict__ W2,
    const float* __restrict__ bout, float* __restrict__ out)
{
  __shared__ __align__(16) u16 As[128 * 32];
  __shared__ __align__(16) u16 Bs[128 * 32];
  int tid = threadIdx.x;
  int n0 = blockIdx.x * 128;
  int m0 = blockIdx.y * 128;
  int lane = tid & 63, wv = tid >> 6;
  int wm = wv >> 1, wn = wv & 1;
  int quad = lane >> 4, l15 = lane & 15;

  f32x4 acc[4][4];
  #pragma unroll
  for (int i = 0; i < 4; ++i)
    #pragma unroll
    for (int j = 0; j < 4; ++j)
      acc[i][j] = (f32x4){0.f, 0.f, 0.f, 0.f};

  // staging: 512 16B-chunks per tile; thread tid does chunks {tid, 256+tid}
  int rsub = tid >> 2, seg = tid & 3;                 // row, 8-elem segment
  const u16* ga0 = A2 + (size_t)(m0 + rsub)      * K2_ + seg * 8;
  const u16* ga1 = A2 + (size_t)(m0 + 64 + rsub) * K2_ + seg * 8;
  const u16* gb0 = W2 + (size_t)(n0 + rsub)      * K2_ + seg * 8;
  const u16* gb1 = W2 + (size_t)(n0 + 64 + rsub) * K2_ + seg * 8;
  u16* lA0 = As + tid * 8;
  u16* lA1 = As + (256 + tid) * 8;
  u16* lB0 = Bs + tid * 8;
  u16* lB1 = Bs + (256 + tid) * 8;

  const u16* arow0 = As + (wm * 64 + l15) * 32 + quad * 8;
  const u16* brow0 = Bs + (wn * 64 + l15) * 32 + quad * 8;

  for (int kc = 0; kc < 56; ++kc){
    __builtin_amdgcn_global_load_lds(ga0, lA0, 16, 0, 0);
    __builtin_amdgcn_global_load_lds(ga1, lA1, 16, 0, 0);
    __builtin_amdgcn_global_load_lds(gb0, lB0, 16, 0, 0);
    __builtin_amdgcn_global_load_lds(gb1, lB1, 16, 0, 0);
    ga0 += 32; ga1 += 32; gb0 += 32; gb1 += 32;
    __syncthreads();
    bf16x8 a[4], b[4];
    #pragma unroll
    for (int i = 0; i < 4; ++i)
      a[i] = *((const bf16x8*)(arow0 + i * 16 * 32));
    #pragma unroll
    for (int j = 0; j < 4; ++j)
      b[j] = *((const bf16x8*)(brow0 + j * 16 * 32));
    #pragma unroll
    for (int i = 0; i < 4; ++i)
      #pragma unroll
      for (int j = 0; j < 4; ++j)
        acc[i][j] = __builtin_amdgcn_mfma_f32_16x16x32_bf16(a[i], b[j], acc[i][j], 0, 0, 0);
    __syncthreads();
  }

  // epilogue: D row = quad*4 + r (m), col = l15 (n)
  int orow = m0 + wm * 64 + quad * 4;
  #pragma unroll
  for (int j = 0; j < 4; ++j){
    int v = n0 + wn * 64 + j * 16 + l15;
    if (v < V_){
      float bo = bout[v];
      #pragma unroll
      for (int i = 0; i < 4; ++i){
        #pragma unroll
        for (int r = 0; r < 4; ++r)
          out[(size_t)(orow + i * 16 + r) * V_ + v] = acc[i][j][r] + bo;
      }
    }
  }
}

extern "C" void kernel_launch(void* const* d_in, const int* in_sizes, int n_in,
                              void* d_out, int out_size, void* d_ws, size_t ws_size,
                              hipStream_t stream)
{
  const float* imf  = (const float*)d_in[0];
  const int*   cap  = (const int*)d_in[1];
  const float* Wh0  = (const float*)d_in[2];
  const float* bh0  = (const float*)d_in[3];
  const float* Wc0  = (const float*)d_in[4];
  const float* bc0  = (const float*)d_in[5];
  const float* Wkey = (const float*)d_in[6];
  // d_in[7] = b_key: softmax-invariant (constant shift per b) -> unused
  const float* emb  = (const float*)d_in[8];
  const float* Wih  = (const float*)d_in[9];
  const float* bih  = (const float*)d_in[10];
  const float* Whh  = (const float*)d_in[11];
  const float* bhh  = (const float*)d_in[12];
  const float* Wout = (const float*)d_in[13];
  const float* bout = (const float*)d_in[14];

  // workspace layout (~53.5 MB)
  float* mean  = (float*)d_ws;            // 65536 f32
  float* hbuf0 = mean  + 65536;           // 32768
  float* hbuf1 = hbuf0 + 32768;           // 32768
  float* cbuf  = hbuf1 + 32768;           // 32768
  float* qk    = cbuf  + 32768;           // 65536
  float* attn  = qk    + 65536;           // 65536
  unsigned int* X  = (unsigned int*)(attn + 65536);  // 4096*896 u32 (dup-packed bf16)
  unsigned int* W2 = X + (size_t)4096 * KX_;         // 10496*896 u32 (hi|lo bf16)

  float* out  = (float*)d_out;
  float* maps = out + (size_t)B_ * T_ * V_;

  k_wsplit<<<9184, 256, 0, stream>>>(Wout, W2);
  k_mean<<<256, 256, 0, stream>>>(imf, mean);
  k_h0c0<<<256, 256, 0, stream>>>(mean, Wh0, bh0, Wc0, bc0, hbuf0, cbuf);
  for (int t = 0; t < T_; ++t){
    const float* q  = (t == 0) ? cbuf : ((t & 1) ? hbuf1 : hbuf0);
    const float* hp = (t & 1) ? hbuf1 : hbuf0;
    float*       hn = (t & 1) ? hbuf0 : hbuf1;
    k_qk  <<<256, 256, 0, stream>>>(q, Wkey, qk);
    k_attn<<<128, 256, 0, stream>>>(imf, qk, cap, emb, attn, X, maps, t);
    k_gates<<<128, 256, 0, stream>>>(Wih, bih, Whh, bhh, cap, emb, attn,
                                     hp, cbuf, hn, X, t);
  }
  k_logits<<<dim3(82, 32), 256, 0, stream>>>((const u16*)X, (const u16*)W2,
                                             bout, out);
}